// Round 10
// baseline (4622.559 us; speedup 1.0000x reference)
//
#include <hip/hip_runtime.h>

// ---------------------------------------------------------------------------
// GraphMessagePassing f32. Thread-per-edge / thread-per-node, fully
// register-blocked MLPs. Weights are read at wave-uniform addresses ->
// compiler emits scalar loads (s_load/L1-broadcast), so the instruction
// stream is ~pure v_fma_f32. No LDS, no shfl.
// ---------------------------------------------------------------------------

__global__ void zero_ws(float* __restrict__ p, int n) {
    int i = blockIdx.x * blockDim.x + threadIdx.x;
    if (i < n) p[i] = 0.0f;
}

// Edge phase: m = b2 + relu(b1 + [node[src], edge[e]] @ w1) @ w2;
// atomicAdd m into agg[dst].
__global__ __launch_bounds__(256) void GraphMessagePassing_5952824672257_kernel(
    const float* __restrict__ nodef,   // [N,64]
    const float* __restrict__ edgef,   // [E,16]
    const int*   __restrict__ eidx,    // [2,E]: src row, dst row
    const float* __restrict__ w1,      // [80,64] row-major
    const float* __restrict__ b1,      // [64]
    const float* __restrict__ w2,      // [64,64]
    const float* __restrict__ b2,      // [64]
    float* __restrict__ agg,           // [N,64] f32, pre-zeroed
    int n_edges, int n_nodes)
{
    const int e = blockIdx.x * 256 + threadIdx.x;
    if (e >= n_edges) return;

    const int d = eidx[n_edges + e];
    int s = eidx[e];
    if (s < 0 || s >= n_nodes) s = 0;   // safety

    float h[64];
    #pragma unroll
    for (int j = 0; j < 64; ++j) h[j] = b1[j];

    // layer 1, node-feature part: k = 0..63
    const float4* xs4 = reinterpret_cast<const float4*>(nodef + (size_t)s * 64);
    #pragma unroll
    for (int c = 0; c < 16; ++c) {
        const float4 x = xs4[c];
        const float xv[4] = {x.x, x.y, x.z, x.w};
        #pragma unroll
        for (int t = 0; t < 4; ++t) {
            const float* wr = w1 + (c * 4 + t) * 64;   // uniform address
            #pragma unroll
            for (int j = 0; j < 64; ++j) h[j] = fmaf(xv[t], wr[j], h[j]);
        }
    }
    // layer 1, edge-feature part: k = 64..79
    const float4* xe4 = reinterpret_cast<const float4*>(edgef + (size_t)e * 16);
    #pragma unroll
    for (int c = 0; c < 4; ++c) {
        const float4 x = xe4[c];
        const float xv[4] = {x.x, x.y, x.z, x.w};
        #pragma unroll
        for (int t = 0; t < 4; ++t) {
            const float* wr = w1 + (64 + c * 4 + t) * 64;
            #pragma unroll
            for (int j = 0; j < 64; ++j) h[j] = fmaf(xv[t], wr[j], h[j]);
        }
    }

    // layer 2
    float m[64];
    #pragma unroll
    for (int j = 0; j < 64; ++j) m[j] = b2[j];
    #pragma unroll
    for (int t = 0; t < 64; ++t) {
        const float ht = fmaxf(h[t], 0.0f);
        const float* wr = w2 + t * 64;                 // uniform address
        #pragma unroll
        for (int j = 0; j < 64; ++j) m[j] = fmaf(ht, wr[j], m[j]);
    }

    float* op = agg + (size_t)d * 64;
    #pragma unroll
    for (int j = 0; j < 64; ++j) atomicAdd(op + j, m[j]);
}

// Node phase: out = relu(b1 + [node, agg] @ w_u1) @ w_u2 + b_u2.
__global__ __launch_bounds__(256) void node_mlp(
    const float* __restrict__ nodef,   // [N,64]
    const float* __restrict__ agg,     // [N,64]
    const float* __restrict__ w1,      // [128,64]
    const float* __restrict__ b1,      // [64]
    const float* __restrict__ w2,      // [64,64]
    const float* __restrict__ b2,      // [64]
    float* __restrict__ out,           // [N,64]
    int n_nodes)
{
    const int n = blockIdx.x * 256 + threadIdx.x;
    if (n >= n_nodes) return;

    float h[64];
    #pragma unroll
    for (int j = 0; j < 64; ++j) h[j] = b1[j];

    const float4* xs4 = reinterpret_cast<const float4*>(nodef + (size_t)n * 64);
    #pragma unroll
    for (int c = 0; c < 16; ++c) {
        const float4 x = xs4[c];
        const float xv[4] = {x.x, x.y, x.z, x.w};
        #pragma unroll
        for (int t = 0; t < 4; ++t) {
            const float* wr = w1 + (c * 4 + t) * 64;
            #pragma unroll
            for (int j = 0; j < 64; ++j) h[j] = fmaf(xv[t], wr[j], h[j]);
        }
    }
    const float4* xa4 = reinterpret_cast<const float4*>(agg + (size_t)n * 64);
    #pragma unroll
    for (int c = 0; c < 16; ++c) {
        const float4 x = xa4[c];
        const float xv[4] = {x.x, x.y, x.z, x.w};
        #pragma unroll
        for (int t = 0; t < 4; ++t) {
            const float* wr = w1 + (64 + c * 4 + t) * 64;
            #pragma unroll
            for (int j = 0; j < 64; ++j) h[j] = fmaf(xv[t], wr[j], h[j]);
        }
    }

    float m[64];
    #pragma unroll
    for (int j = 0; j < 64; ++j) m[j] = b2[j];
    #pragma unroll
    for (int t = 0; t < 64; ++t) {
        const float ht = fmaxf(h[t], 0.0f);
        const float* wr = w2 + t * 64;
        #pragma unroll
        for (int j = 0; j < 64; ++j) m[j] = fmaf(ht, wr[j], m[j]);
    }

    float4* op = reinterpret_cast<float4*>(out + (size_t)n * 64);
    #pragma unroll
    for (int c = 0; c < 16; ++c)
        op[c] = make_float4(m[c * 4], m[c * 4 + 1], m[c * 4 + 2], m[c * 4 + 3]);
}

extern "C" void kernel_launch(void* const* d_in, const int* in_sizes, int n_in,
                              void* d_out, int out_size, void* d_ws, size_t ws_size,
                              hipStream_t stream) {
    const float* nodef = (const float*)d_in[0];
    const float* edgef = (const float*)d_in[1];
    const int*   eidx  = (const int*)d_in[2];
    const float* w_m1  = (const float*)d_in[3];
    const float* b_m1  = (const float*)d_in[4];
    const float* w_m2  = (const float*)d_in[5];
    const float* b_m2  = (const float*)d_in[6];
    const float* w_u1  = (const float*)d_in[7];
    const float* b_u1  = (const float*)d_in[8];
    const float* w_u2  = (const float*)d_in[9];
    const float* b_u2  = (const float*)d_in[10];
    float* out = (float*)d_out;

    const int n_nodes = out_size / 64;
    const int n_edges = in_sizes[2] / 2;
    const int threads = 256;

    float* agg = (float*)d_ws;   // [N,64] f32 (12.8 MB of 320 MB ws)
    const int zn = n_nodes * 64;
    zero_ws<<<(zn + threads - 1) / threads, threads, 0, stream>>>(agg, zn);

    GraphMessagePassing_5952824672257_kernel<<<
        (n_edges + threads - 1) / threads, threads, 0, stream>>>(
        nodef, edgef, eidx, w_m1, b_m1, w_m2, b_m2, agg, n_edges, n_nodes);

    node_mlp<<<(n_nodes + threads - 1) / threads, threads, 0, stream>>>(
        nodef, agg, w_u1, b_u1, w_u2, b_u2, out, n_nodes);
}